// Round 4
// baseline (248.162 us; speedup 1.0000x reference)
//
#include <hip/hip_runtime.h>
#include <hip/hip_bf16.h>

#define BT    8192      // B*T tokens (4*2048)
#define SEQ_T 2048
#define DIN   1024
#define NH    16
#define NK    8
#define DH    64
#define DO    64
#define GRID  768       // 3 blocks/CU guaranteed: launch_bounds(256,3) + 52KB LDS

typedef __bf16 bf16;
typedef __attribute__((ext_vector_type(8))) __bf16 bf16x8;
typedef __attribute__((ext_vector_type(4))) __bf16 bf16x4;
typedef __attribute__((ext_vector_type(4))) float floatx4;

// ---------------------------------------------------------------------------
// Software grid barrier (graph-capture-safe, no cooperative launch).
// Ticket scheme: robust to the counter starting at any multiple of GRID, so
// back-to-back graph replays are safe even without the memset; the memset in
// kernel_launch resets the poison each capture/replay.
// __threadfence() = device-scope fence (L2 writeback) so phase-A stores to
// wt/scores_t are visible across XCDs before phase B reads them.
// ---------------------------------------------------------------------------
__device__ __forceinline__ void grid_sync(unsigned* cnt) {
  __syncthreads();
  if (threadIdx.x == 0) {
    __threadfence();
    unsigned v = __hip_atomic_fetch_add(cnt, 1u, __ATOMIC_ACQ_REL,
                                        __HIP_MEMORY_SCOPE_AGENT);
    unsigned target = (v / GRID + 1u) * GRID;
    while (__hip_atomic_load(cnt, __ATOMIC_ACQUIRE,
                             __HIP_MEMORY_SCOPE_AGENT) < target)
      __builtin_amdgcn_s_sleep(2);
    __threadfence();
  }
  __syncthreads();
}

// ---------------------------------------------------------------------------
// Fused kernel (v10) — phase logic identical to verified v8.
// Phase A1: scores, grid-stride (8 token-quads per CU, balanced).
// Phase A2: W transpose, blocks 0..127 (LDS tile aliased into wl).
// grid_sync
// Phase B: v8 moe body, grid-stride (8 output tiles per CU, balanced).
// LDS: xl 16K + wl 32K + sl 4K = 52 KB.
// ---------------------------------------------------------------------------
__global__ __launch_bounds__(256, 3) void fused_kernel(
    const float* __restrict__ x, const float* __restrict__ weight,
    const float* __restrict__ diag, const float* __restrict__ phi,
    bf16* __restrict__ wt, float* __restrict__ scores_t,
    float* __restrict__ out, unsigned* __restrict__ cnt)
{
  __shared__ bf16  xl[128 * 64];        // 16384 B
  __shared__ bf16  wl[256 * 64];        // 32768 B
  __shared__ float sl[NK * 128];        //  4096 B

  int b = blockIdx.x, tid = threadIdx.x;
  int wave = tid >> 6, lane = tid & 63;

  // ================= phase A1: scores, one wave per token =================
  for (int tq = b; tq < BT / 4; tq += GRID) {
    int token = tq * 4 + wave;
    const floatx4* xr = (const floatx4*)(x + (size_t)token * DIN);
    const floatx4* dg = (const floatx4*)diag;
    floatx4 acc[NK];
#pragma unroll
    for (int k = 0; k < NK; k++) acc[k] = (floatx4){0.f, 0.f, 0.f, 0.f};
#pragma unroll
    for (int it = 0; it < 4; it++) {
      floatx4 xv = xr[it * 64 + lane];
#pragma unroll
      for (int k = 0; k < NK; k++) {
        floatx4 dv = dg[k * 256 + it * 64 + lane];
        acc[k] += xv * dv;
      }
    }
    float r[NK];
#pragma unroll
    for (int k = 0; k < NK; k++)
      r[k] = (acc[k][0] + acc[k][1]) + (acc[k][2] + acc[k][3]);
#pragma unroll
    for (int k = 0; k < NK; k++) {
      float v = r[k];
#pragma unroll
      for (int off = 32; off >= 1; off >>= 1) v += __shfl_xor(v, off, 64);
      r[k] = v;
    }
    if (lane == 0) {
      int t = token & (SEQ_T - 1);
#pragma unroll
      for (int k = 0; k < NK; k++)
        scores_t[(size_t)k * BT + token] = phi[t * NK + k] + r[k];
    }
  }

  // ================= phase A2: W transpose, blocks 0..127 =================
  if (b < NH * NK) {
    bf16* tile = wl;                    // 64*68*2 = 8704 B, aliased into wl
    const float* wsrc = weight + (size_t)b * DH * DO;
#pragma unroll
    for (int it = 0; it < 4; it++) {
      int idx = it * 1024 + tid * 4;
      int i = idx >> 6, o = idx & 63;
      floatx4 v = *(const floatx4*)(wsrc + idx);
#pragma unroll
      for (int r = 0; r < 4; r++)
        tile[(o + r) * 68 + i] = (bf16)v[r];
    }
    __syncthreads();
#pragma unroll
    for (int it = 0; it < 4; it++) {
      int idx = it * 1024 + tid * 4;
      int o2 = idx >> 6, i2 = idx & 63;
      bf16x4 v = *(const bf16x4*)&tile[o2 * 68 + i2];
      *(bf16x4*)(wt + (size_t)b * 4096 + idx) = v;
    }
  }

  // ============ grid-wide barrier: publish wt + scores_t ============
  grid_sync(cnt);

  // ================= phase B: moe tiles, grid-stride =================
  int l15 = lane & 15, q = lane >> 4, w = tid >> 6;
  int mh = w >> 1;              // token half (64 rows)
  int ns = w & 1;               // 16-col slice within the 32-col half

  for (int t5 = b; t5 < 64 * NH * 2; t5 += GRID) {
    int g  = t5 >> 5;           // 0..63  (128-token groups)
    int h  = (t5 >> 1) & 15;
    int nh = t5 & 1;            // col half

    __syncthreads();            // protect LDS from previous iteration readers

    // ---- stage x tile from fp32 source: convert + swizzle ----
    {
      const float* xs = x + (size_t)(g * 128) * DIN + h * 64;
#pragma unroll
      for (int it = 0; it < 4; it++) {
        int idx = it * 256 + tid;           // chunk id 0..1023
        int row = idx >> 3, c = idx & 7;    // chunk = 8 bf16 = 32 B of fp32
        const float* p = xs + (size_t)row * DIN + c * 8;
        floatx4 u0 = *(const floatx4*)p;
        floatx4 u1 = *(const floatx4*)(p + 4);
        bf16x8 v;
        v[0] = (bf16)u0[0]; v[1] = (bf16)u0[1];
        v[2] = (bf16)u0[2]; v[3] = (bf16)u0[3];
        v[4] = (bf16)u1[0]; v[5] = (bf16)u1[1];
        v[6] = (bf16)u1[2]; v[7] = (bf16)u1[3];
        int pc = c ^ (row & 7);
        *(bf16x8*)(xl + row * 64 + pc * 8) = v;
      }
    }
    // ---- stage W half: 8 experts x 32 o-rows x 64, swizzled ----
    {
#pragma unroll
      for (int it = 0; it < 8; it++) {
        int idx = it * 256 + tid;               // 0..2047
        int R = idx >> 3, c = idx & 7;          // R = e*32 + o
        int e = R >> 5, o = R & 31;
        bf16x8 v = *(const bf16x8*)(wt + ((size_t)(h * NK + e) * DO + nh * 32 + o) * 64 + c * 8);
        int pc = c ^ (R & 7);
        *(bf16x8*)(wl + R * 64 + pc * 8) = v;
      }
    }
    // ---- stage scores: 8 experts x 128 tokens fp32 ----
    {
      int k = tid >> 5, t4 = (tid & 31) * 4;
      floatx4 v = *(const floatx4*)(scores_t + (size_t)k * BT + g * 128 + t4);
      *(floatx4*)(sl + k * 128 + t4) = v;
    }
    __syncthreads();

    // ---- B fragments: B[i=ki*32+q*8+j][o=ns*16+l15], all 8 experts ----
    bf16x8 bfr[NK][2];
#pragma unroll
    for (int e = 0; e < NK; e++) {
      int R = e * 32 + ns * 16 + l15;
#pragma unroll
      for (int ki = 0; ki < 2; ki++) {
        int pc = (ki * 4 + q) ^ (R & 7);
        bfr[e][ki] = *(const bf16x8*)(wl + R * 64 + pc * 8);
      }
    }

#pragma unroll
    for (int m = 0; m < 4; m++) {
      int tr = mh * 64 + m * 16;                 // token row base in block
      int row = tr + l15;
      int p0 = q ^ (row & 7), p1 = (q + 4) ^ (row & 7);
      bf16x8 a0 = *(const bf16x8*)(xl + row * 64 + p0 * 8);
      bf16x8 a1 = *(const bf16x8*)(xl + row * 64 + p1 * 8);
      floatx4 y = (floatx4){0.f, 0.f, 0.f, 0.f};
#pragma unroll
      for (int e = 0; e < NK; e++) {
        floatx4 s4 = *(const floatx4*)(sl + e * 128 + tr + q * 4);
        floatx4 z = (floatx4){0.f, 0.f, 0.f, 0.f};
        z = __builtin_amdgcn_mfma_f32_16x16x32_bf16(a0, bfr[e][0], z, 0, 0, 0);
        z = __builtin_amdgcn_mfma_f32_16x16x32_bf16(a1, bfr[e][1], z, 0, 0, 0);
        y += s4 * z;
      }
      // store: C/D layout col=l15, row=q*4+r
      int orow = g * 128 + tr + q * 4;
      float* op = out + (size_t)orow * (NH * DO) + h * DO + nh * 32 + ns * 16 + l15;
#pragma unroll
      for (int r = 0; r < 4; r++)
        op[(size_t)r * (NH * DO)] = y[r];
    }
  }
}

extern "C" void kernel_launch(void* const* d_in, const int* in_sizes, int n_in,
                              void* d_out, int out_size, void* d_ws, size_t ws_size,
                              hipStream_t stream) {
  const float* x      = (const float*)d_in[0];
  const float* weight = (const float*)d_in[1];
  const float* diag   = (const float*)d_in[2];
  const float* phi    = (const float*)d_in[3];
  float* out = (float*)d_out;

  // workspace: [0,1MiB) wt | [2MiB) scores_t 256KiB | [3MiB) barrier counter
  bf16*     wt       = (bf16*)d_ws;
  float*    scores_t = (float*)((char*)d_ws + (2u << 20));
  unsigned* cnt      = (unsigned*)((char*)d_ws + (3u << 20));

  hipMemsetAsync(cnt, 0, 64, stream);   // graph-capturable reset of poison
  fused_kernel<<<GRID, 256, 0, stream>>>(x, weight, diag, phi, wt, scores_t,
                                         out, cnt);
}

// Round 5
// 221.514 us; speedup vs baseline: 1.1203x; 1.1203x over previous
//
#include <hip/hip_runtime.h>
#include <hip/hip_bf16.h>

#define BT    8192      // B*T tokens (4*2048)
#define SEQ_T 2048
#define DIN   1024
#define NH    16
#define NK    8
#define DH    64
#define DO    64
#define GRID  768       // 3 blocks/CU guaranteed: launch_bounds(256,3) + 52KB LDS

typedef __bf16 bf16;
typedef __attribute__((ext_vector_type(8))) __bf16 bf16x8;
typedef __attribute__((ext_vector_type(4))) __bf16 bf16x4;
typedef __attribute__((ext_vector_type(4))) float floatx4;

// ---------------------------------------------------------------------------
// Contention-free software grid barrier.
// R4 lesson: agent-scope ACQUIRE loads emit buffer_inv per poll -> 767
// spinners continuously invalidated every XCD's L1/L2 for the whole phase-A
// duration (183us dispatch, 3% VALUBusy). Fix: RELAXED add + RELAXED polls
// (no cache maintenance), ~1us poll period via s_sleep, and exactly ONE
// release fence before the add / ONE acquire fence after the spin exits.
// Ticket scheme stays replay-safe given the memset in kernel_launch.
// ---------------------------------------------------------------------------
__device__ __forceinline__ void grid_sync(unsigned* cnt) {
  __syncthreads();
  if (threadIdx.x == 0) {
    __threadfence();                     // release: publish wt/scores_t (wbL2)
    unsigned v = __hip_atomic_fetch_add(cnt, 1u, __ATOMIC_RELAXED,
                                        __HIP_MEMORY_SCOPE_AGENT);
    unsigned target = (v / GRID + 1u) * GRID;
    while (__hip_atomic_load(cnt, __ATOMIC_RELAXED,
                             __HIP_MEMORY_SCOPE_AGENT) < target)
      __builtin_amdgcn_s_sleep(32);      // ~0.9us between polls
    __threadfence();                     // acquire: one inv, then read
  }
  __syncthreads();
}

// ---------------------------------------------------------------------------
// Fused kernel (v11) — phase logic identical to verified v8/v10.
// Phase A1: scores, grid-stride (balanced). Phase A2: W transpose, blocks
// 0..127. grid_sync. Phase B: v8 moe body, grid-stride.
// LDS: xl 16K + wl 32K + sl 4K = 52 KB.
// ---------------------------------------------------------------------------
__global__ __launch_bounds__(256, 3) void fused_kernel(
    const float* __restrict__ x, const float* __restrict__ weight,
    const float* __restrict__ diag, const float* __restrict__ phi,
    bf16* __restrict__ wt, float* __restrict__ scores_t,
    float* __restrict__ out, unsigned* __restrict__ cnt)
{
  __shared__ bf16  xl[128 * 64];        // 16384 B
  __shared__ bf16  wl[256 * 64];        // 32768 B
  __shared__ float sl[NK * 128];        //  4096 B

  int b = blockIdx.x, tid = threadIdx.x;
  int wave = tid >> 6, lane = tid & 63;

  // ================= phase A1: scores, one wave per token =================
  for (int tq = b; tq < BT / 4; tq += GRID) {
    int token = tq * 4 + wave;
    const floatx4* xr = (const floatx4*)(x + (size_t)token * DIN);
    const floatx4* dg = (const floatx4*)diag;
    floatx4 acc[NK];
#pragma unroll
    for (int k = 0; k < NK; k++) acc[k] = (floatx4){0.f, 0.f, 0.f, 0.f};
#pragma unroll
    for (int it = 0; it < 4; it++) {
      floatx4 xv = xr[it * 64 + lane];
#pragma unroll
      for (int k = 0; k < NK; k++) {
        floatx4 dv = dg[k * 256 + it * 64 + lane];
        acc[k] += xv * dv;
      }
    }
    float r[NK];
#pragma unroll
    for (int k = 0; k < NK; k++)
      r[k] = (acc[k][0] + acc[k][1]) + (acc[k][2] + acc[k][3]);
#pragma unroll
    for (int k = 0; k < NK; k++) {
      float v = r[k];
#pragma unroll
      for (int off = 32; off >= 1; off >>= 1) v += __shfl_xor(v, off, 64);
      r[k] = v;
    }
    if (lane == 0) {
      int t = token & (SEQ_T - 1);
#pragma unroll
      for (int k = 0; k < NK; k++)
        scores_t[(size_t)k * BT + token] = phi[t * NK + k] + r[k];
    }
  }

  // ================= phase A2: W transpose, blocks 0..127 =================
  if (b < NH * NK) {
    bf16* tile = wl;                    // 64*68*2 = 8704 B, aliased into wl
    const float* wsrc = weight + (size_t)b * DH * DO;
#pragma unroll
    for (int it = 0; it < 4; it++) {
      int idx = it * 1024 + tid * 4;
      int i = idx >> 6, o = idx & 63;
      floatx4 v = *(const floatx4*)(wsrc + idx);
#pragma unroll
      for (int r = 0; r < 4; r++)
        tile[(o + r) * 68 + i] = (bf16)v[r];
    }
    __syncthreads();
#pragma unroll
    for (int it = 0; it < 4; it++) {
      int idx = it * 1024 + tid * 4;
      int o2 = idx >> 6, i2 = idx & 63;
      bf16x4 v = *(const bf16x4*)&tile[o2 * 68 + i2];
      *(bf16x4*)(wt + (size_t)b * 4096 + idx) = v;
    }
  }

  // ============ grid-wide barrier: publish wt + scores_t ============
  grid_sync(cnt);

  // ================= phase B: moe tiles, grid-stride =================
  int l15 = lane & 15, q = lane >> 4, w = tid >> 6;
  int mh = w >> 1;              // token half (64 rows)
  int ns = w & 1;               // 16-col slice within the 32-col half

  for (int t5 = b; t5 < 64 * NH * 2; t5 += GRID) {
    int g  = t5 >> 5;           // 0..63  (128-token groups)
    int h  = (t5 >> 1) & 15;
    int nh = t5 & 1;            // col half

    __syncthreads();            // protect LDS from previous iteration readers

    // ---- stage x tile from fp32 source: convert + swizzle ----
    {
      const float* xs = x + (size_t)(g * 128) * DIN + h * 64;
#pragma unroll
      for (int it = 0; it < 4; it++) {
        int idx = it * 256 + tid;           // chunk id 0..1023
        int row = idx >> 3, c = idx & 7;    // chunk = 8 bf16 = 32 B of fp32
        const float* p = xs + (size_t)row * DIN + c * 8;
        floatx4 u0 = *(const floatx4*)p;
        floatx4 u1 = *(const floatx4*)(p + 4);
        bf16x8 v;
        v[0] = (bf16)u0[0]; v[1] = (bf16)u0[1];
        v[2] = (bf16)u0[2]; v[3] = (bf16)u0[3];
        v[4] = (bf16)u1[0]; v[5] = (bf16)u1[1];
        v[6] = (bf16)u1[2]; v[7] = (bf16)u1[3];
        int pc = c ^ (row & 7);
        *(bf16x8*)(xl + row * 64 + pc * 8) = v;
      }
    }
    // ---- stage W half: 8 experts x 32 o-rows x 64, swizzled ----
    {
#pragma unroll
      for (int it = 0; it < 8; it++) {
        int idx = it * 256 + tid;               // 0..2047
        int R = idx >> 3, c = idx & 7;          // R = e*32 + o
        int e = R >> 5, o = R & 31;
        bf16x8 v = *(const bf16x8*)(wt + ((size_t)(h * NK + e) * DO + nh * 32 + o) * 64 + c * 8);
        int pc = c ^ (R & 7);
        *(bf16x8*)(wl + R * 64 + pc * 8) = v;
      }
    }
    // ---- stage scores: 8 experts x 128 tokens fp32 ----
    {
      int k = tid >> 5, t4 = (tid & 31) * 4;
      floatx4 v = *(const floatx4*)(scores_t + (size_t)k * BT + g * 128 + t4);
      *(floatx4*)(sl + k * 128 + t4) = v;
    }
    __syncthreads();

    // ---- B fragments: B[i=ki*32+q*8+j][o=ns*16+l15], all 8 experts ----
    bf16x8 bfr[NK][2];
#pragma unroll
    for (int e = 0; e < NK; e++) {
      int R = e * 32 + ns * 16 + l15;
#pragma unroll
      for (int ki = 0; ki < 2; ki++) {
        int pc = (ki * 4 + q) ^ (R & 7);
        bfr[e][ki] = *(const bf16x8*)(wl + R * 64 + pc * 8);
      }
    }

#pragma unroll
    for (int m = 0; m < 4; m++) {
      int tr = mh * 64 + m * 16;                 // token row base in block
      int row = tr + l15;
      int p0 = q ^ (row & 7), p1 = (q + 4) ^ (row & 7);
      bf16x8 a0 = *(const bf16x8*)(xl + row * 64 + p0 * 8);
      bf16x8 a1 = *(const bf16x8*)(xl + row * 64 + p1 * 8);
      floatx4 y = (floatx4){0.f, 0.f, 0.f, 0.f};
#pragma unroll
      for (int e = 0; e < NK; e++) {
        floatx4 s4 = *(const floatx4*)(sl + e * 128 + tr + q * 4);
        floatx4 z = (floatx4){0.f, 0.f, 0.f, 0.f};
        z = __builtin_amdgcn_mfma_f32_16x16x32_bf16(a0, bfr[e][0], z, 0, 0, 0);
        z = __builtin_amdgcn_mfma_f32_16x16x32_bf16(a1, bfr[e][1], z, 0, 0, 0);
        y += s4 * z;
      }
      // store: C/D layout col=l15, row=q*4+r
      int orow = g * 128 + tr + q * 4;
      float* op = out + (size_t)orow * (NH * DO) + h * DO + nh * 32 + ns * 16 + l15;
#pragma unroll
      for (int r = 0; r < 4; r++)
        op[(size_t)r * (NH * DO)] = y[r];
    }
  }
}

extern "C" void kernel_launch(void* const* d_in, const int* in_sizes, int n_in,
                              void* d_out, int out_size, void* d_ws, size_t ws_size,
                              hipStream_t stream) {
  const float* x      = (const float*)d_in[0];
  const float* weight = (const float*)d_in[1];
  const float* diag   = (const float*)d_in[2];
  const float* phi    = (const float*)d_in[3];
  float* out = (float*)d_out;

  // workspace: [0,1MiB) wt | [2MiB) scores_t 256KiB | [3MiB) barrier counter
  bf16*     wt       = (bf16*)d_ws;
  float*    scores_t = (float*)((char*)d_ws + (2u << 20));
  unsigned* cnt      = (unsigned*)((char*)d_ws + (3u << 20));

  hipMemsetAsync(cnt, 0, 64, stream);   // graph-capturable reset of poison
  fused_kernel<<<GRID, 256, 0, stream>>>(x, weight, diag, phi, wt, scores_t,
                                         out, cnt);
}

// Round 6
// 129.904 us; speedup vs baseline: 1.9104x; 1.7052x over previous
//
#include <hip/hip_runtime.h>
#include <hip/hip_bf16.h>

#define BT    8192      // B*T tokens (4*2048)
#define SEQ_T 2048
#define DIN   1024
#define NH    16
#define NK    8
#define DH    64
#define DO    64

typedef __bf16 bf16;
typedef __attribute__((ext_vector_type(8))) __bf16 bf16x8;
typedef __attribute__((ext_vector_type(4))) __bf16 bf16x4;
typedef __attribute__((ext_vector_type(4))) float floatx4;

// ---------------------------------------------------------------------------
// Kernel 1 (v6 prep, verified): scores + head-major bf16 xh + W transpose
// ---------------------------------------------------------------------------
__global__ __launch_bounds__(256) void prep_kernel(
    const float* __restrict__ x, const float* __restrict__ weight,
    const float* __restrict__ diag, const float* __restrict__ phi,
    float* __restrict__ scores_t, bf16* __restrict__ wt, bf16* __restrict__ xh)
{
  int blk = blockIdx.x, tid = threadIdx.x;
  if (blk < BT / 4) {
    // ---- scores + head-major bf16 copy: one wave per token ----
    int wave = tid >> 6, lane = tid & 63;
    int token = blk * 4 + wave;
    const floatx4* xr = (const floatx4*)(x + (size_t)token * DIN);
    const floatx4* dg = (const floatx4*)diag;
    floatx4 acc[NK];
#pragma unroll
    for (int k = 0; k < NK; k++) acc[k] = (floatx4){0.f, 0.f, 0.f, 0.f};
#pragma unroll
    for (int it = 0; it < 4; it++) {
      floatx4 xv = xr[it * 64 + lane];
      int col = it * 256 + lane * 4;
      int h = col >> 6, c = col & 63;
      bf16x4 cv;
      cv[0] = (bf16)xv[0]; cv[1] = (bf16)xv[1];
      cv[2] = (bf16)xv[2]; cv[3] = (bf16)xv[3];
      *(bf16x4*)(xh + ((size_t)h * BT + token) * 64 + c) = cv;
#pragma unroll
      for (int k = 0; k < NK; k++) {
        floatx4 dv = dg[k * 256 + it * 64 + lane];
        acc[k] += xv * dv;
      }
    }
    float r[NK];
#pragma unroll
    for (int k = 0; k < NK; k++)
      r[k] = (acc[k][0] + acc[k][1]) + (acc[k][2] + acc[k][3]);
#pragma unroll
    for (int k = 0; k < NK; k++) {
      float v = r[k];
#pragma unroll
      for (int off = 32; off >= 1; off >>= 1) v += __shfl_xor(v, off, 64);
      r[k] = v;
    }
    if (lane == 0) {
      int t = token & (SEQ_T - 1);
#pragma unroll
      for (int k = 0; k < NK; k++)
        scores_t[(size_t)k * BT + token] = phi[t * NK + k] + r[k];
    }
  } else {
    // ---- weight transpose: one (h,k) 64x64 tile per block, coalesced ----
    __shared__ bf16 tile[64 * 68];
    int hk = blk - BT / 4;
    const float* wsrc = weight + (size_t)hk * DH * DO;
#pragma unroll
    for (int it = 0; it < 4; it++) {
      int idx = it * 1024 + tid * 4;
      int i = idx >> 6, o = idx & 63;
      floatx4 v = *(const floatx4*)(wsrc + idx);
#pragma unroll
      for (int r = 0; r < 4; r++)
        tile[(o + r) * 68 + i] = (bf16)v[r];
    }
    __syncthreads();
#pragma unroll
    for (int it = 0; it < 4; it++) {
      int idx = it * 1024 + tid * 4;
      int o2 = idx >> 6, i2 = idx & 63;
      bf16x4 v = *(const bf16x4*)&tile[o2 * 68 + i2];
      *(bf16x4*)(wt + (size_t)hk * 4096 + idx) = v;
    }
  }
}

// ---------------------------------------------------------------------------
// Kernel 2 (v12): ZERO-LDS moe. All MFMA fragments loaded directly from
// global with per-lane addresses (identical unswizzled element mapping to
// the verified v6/v8 LDS path):
//   B[e][ki]: wt[((h*8+e)*64 + nh*32+ns*16+l15)*64 + ki*32 + q*8 .. +8]
//   A  (m)  : xh[(h*BT + g*128 + tr+l15)*64 + q*8 (+32)]
//   S  (m,e): scores_t[e*BT + g*128 + tr + q*4 ..]  (l15-uniform, L1 bcast)
// wt (1 MB) and xh tiles are L2-resident; re-reads are cache-served.
// No __syncthreads, no ds ops, LDS=0 -> occupancy VGPR-bound (~4 blk/CU),
// ~56 independent global loads per lane fully pipelined against 64 MFMA.
// ---------------------------------------------------------------------------
__global__ __launch_bounds__(256) void moe_kernel(
    const bf16* __restrict__ xh, const bf16* __restrict__ wt,
    const float* __restrict__ scores_t, float* __restrict__ out)
{
  int bid = blockIdx.x;
  int g  = bid >> 5;            // 0..63  (128-token groups)
  int h  = (bid >> 1) & 15;
  int nh = bid & 1;             // col half (32 of the head's 64 out-cols)
  int tid = threadIdx.x, lane = tid & 63, w = tid >> 6;
  int l15 = lane & 15, q = lane >> 4;
  int mh = w >> 1;              // token half (64 rows)
  int ns = w & 1;               // 16-col slice within the 32-col half

  // ---- B fragments: 16 direct 16-B loads, issued up front ----
  bf16x8 b[NK][2];
  const bf16* wb = wt + ((size_t)(h * NK) * DO + nh * 32 + ns * 16 + l15) * 64
                      + q * 8;
#pragma unroll
  for (int e = 0; e < NK; e++) {
#pragma unroll
    for (int ki = 0; ki < 2; ki++)
      b[e][ki] = *(const bf16x8*)(wb + (size_t)e * DO * 64 + ki * 32);
  }

  const bf16*  xa = xh + ((size_t)h * BT + g * 128) * 64;
  const float* ss = scores_t + g * 128;

#pragma unroll
  for (int m = 0; m < 4; m++) {
    int tr = mh * 64 + m * 16;                 // token row base in block
    int row = tr + l15;
    bf16x8 a0 = *(const bf16x8*)(xa + (size_t)row * 64 + q * 8);
    bf16x8 a1 = *(const bf16x8*)(xa + (size_t)row * 64 + q * 8 + 32);
    floatx4 y = (floatx4){0.f, 0.f, 0.f, 0.f};
#pragma unroll
    for (int e = 0; e < NK; e++) {
      floatx4 s4 = *(const floatx4*)(ss + (size_t)e * BT + tr + q * 4);
      floatx4 z = (floatx4){0.f, 0.f, 0.f, 0.f};
      z = __builtin_amdgcn_mfma_f32_16x16x32_bf16(a0, b[e][0], z, 0, 0, 0);
      z = __builtin_amdgcn_mfma_f32_16x16x32_bf16(a1, b[e][1], z, 0, 0, 0);
      y += s4 * z;
    }
    // store: C/D layout col=l15, row=q*4+r
    int orow = g * 128 + tr + q * 4;
    float* op = out + (size_t)orow * (NH * DO) + h * DO + nh * 32 + ns * 16 + l15;
#pragma unroll
    for (int r = 0; r < 4; r++)
      op[(size_t)r * (NH * DO)] = y[r];
  }
}

extern "C" void kernel_launch(void* const* d_in, const int* in_sizes, int n_in,
                              void* d_out, int out_size, void* d_ws, size_t ws_size,
                              hipStream_t stream) {
  const float* x      = (const float*)d_in[0];
  const float* weight = (const float*)d_in[1];
  const float* diag   = (const float*)d_in[2];
  const float* phi    = (const float*)d_in[3];
  float* out = (float*)d_out;

  // workspace: [0,1MiB) wt dense | [2MiB) scores_t 256KiB | [4MiB) xh 16MiB
  bf16*  wt       = (bf16*)d_ws;
  float* scores_t = (float*)((char*)d_ws + (2u << 20));
  bf16*  xh       = (bf16*)((char*)d_ws + (4u << 20));

  prep_kernel<<<BT / 4 + NH * NK, 256, 0, stream>>>(x, weight, diag, phi,
                                                    scores_t, wt, xh);
  // 64 token-groups x 16 heads x 2 col-halves
  moe_kernel<<<64 * NH * 2, 256, 0, stream>>>(xh, wt, scores_t, out);
}

// Round 7
// 108.584 us; speedup vs baseline: 2.2854x; 1.1963x over previous
//
#include <hip/hip_runtime.h>
#include <hip/hip_bf16.h>

#define BT    8192      // B*T tokens (4*2048)
#define SEQ_T 2048
#define DIN   1024
#define NH    16
#define NK    8
#define DH    64
#define DO    64

typedef __bf16 bf16;
typedef __attribute__((ext_vector_type(8))) __bf16 bf16x8;
typedef __attribute__((ext_vector_type(4))) __bf16 bf16x4;
typedef __attribute__((ext_vector_type(4))) float floatx4;

// global -> LDS direct DMA, 16 B per lane (dest = wave-uniform base + lane*16)
#define GLOAD_LDS16(gp, lp)                                        \
  __builtin_amdgcn_global_load_lds(                                \
      (__attribute__((address_space(1))) const void*)(gp),         \
      (__attribute__((address_space(3))) void*)(lp), 16, 0, 0)

// ---------------------------------------------------------------------------
// Kernel 1 (v13): scores + PRE-SWIZZLED LDS images of x-tiles and W.
//  - ximg[(g*16+h)] = 128x64 bf16 tile, element (row,i) stored at
//      row*64 + (((i>>3) ^ (row&7))<<3) + (i&7)     (the exact LDS image)
//  - wimg[(h*2+nh)] = 256x64 bf16 (R = e*32+o, o in nh half), element (R,i)
//      at R*64 + (((i>>3) ^ (R&7))<<3) + (i&7)
// moe then stages with global_load_lds (linear dest == stored order) and
// reads with the same XOR swizzle: rule-21 "pre-swizzled source" pattern.
// ---------------------------------------------------------------------------
__global__ __launch_bounds__(256) void prep_kernel(
    const float* __restrict__ x, const float* __restrict__ weight,
    const float* __restrict__ diag, const float* __restrict__ phi,
    float* __restrict__ scores_t, bf16* __restrict__ wimg,
    bf16* __restrict__ ximg)
{
  int blk = blockIdx.x, tid = threadIdx.x;
  if (blk < BT / 4) {
    // ---- scores + swizzled-image bf16 copy: one wave per token ----
    int wave = tid >> 6, lane = tid & 63;
    int token = blk * 4 + wave;
    int row = token & 127, gg = token >> 7;
    const floatx4* xr = (const floatx4*)(x + (size_t)token * DIN);
    const floatx4* dg = (const floatx4*)diag;
    floatx4 acc[NK];
#pragma unroll
    for (int k = 0; k < NK; k++) acc[k] = (floatx4){0.f, 0.f, 0.f, 0.f};
#pragma unroll
    for (int it = 0; it < 4; it++) {
      floatx4 xv = xr[it * 64 + lane];
      int col = it * 256 + lane * 4;
      int h = col >> 6, c = col & 63;
      bf16x4 cv;
      cv[0] = (bf16)xv[0]; cv[1] = (bf16)xv[1];
      cv[2] = (bf16)xv[2]; cv[3] = (bf16)xv[3];
      int a = (((c >> 3) ^ (row & 7)) << 3) + (c & 7);
      *(bf16x4*)(ximg + ((size_t)(gg * 16 + h) * 128 + row) * 64 + a) = cv;
#pragma unroll
      for (int k = 0; k < NK; k++) {
        floatx4 dv = dg[k * 256 + it * 64 + lane];
        acc[k] += xv * dv;
      }
    }
    float r[NK];
#pragma unroll
    for (int k = 0; k < NK; k++)
      r[k] = (acc[k][0] + acc[k][1]) + (acc[k][2] + acc[k][3]);
#pragma unroll
    for (int k = 0; k < NK; k++) {
      float v = r[k];
#pragma unroll
      for (int off = 32; off >= 1; off >>= 1) v += __shfl_xor(v, off, 64);
      r[k] = v;
    }
    if (lane == 0) {
      int t = token & (SEQ_T - 1);
#pragma unroll
      for (int k = 0; k < NK; k++)
        scores_t[(size_t)k * BT + token] = phi[t * NK + k] + r[k];
    }
  } else {
    // ---- weight transpose -> swizzled image: one (h,k) tile per block ----
    __shared__ bf16 tile[64 * 68];
    int hk = blk - BT / 4;
    int h = hk >> 3, k = hk & 7;
    const float* wsrc = weight + (size_t)hk * DH * DO;
#pragma unroll
    for (int it = 0; it < 4; it++) {
      int idx = it * 1024 + tid * 4;
      int i = idx >> 6, o = idx & 63;
      floatx4 v = *(const floatx4*)(wsrc + idx);
#pragma unroll
      for (int r = 0; r < 4; r++)
        tile[(o + r) * 68 + i] = (bf16)v[r];
    }
    __syncthreads();
#pragma unroll
    for (int it = 0; it < 4; it++) {
      int idx = it * 1024 + tid * 4;
      int o2 = idx >> 6, i2 = idx & 63;
      bf16x4 v = *(const bf16x4*)&tile[o2 * 68 + i2];
      int nh = o2 >> 5, o = o2 & 31, R = k * 32 + o;
      int a = (((i2 >> 3) ^ (R & 7)) << 3) + (i2 & 7);
      *(bf16x4*)(wimg + ((size_t)(h * 2 + nh) * 256 + R) * 64 + a) = v;
    }
  }
}

// ---------------------------------------------------------------------------
// Kernel 2 (v13): v6 compute (verified), staging via global_load_lds x16.
// 13 DMA issues/thread, zero VGPR round-trip, zero ds_write; loads stay in
// flight until the barrier's vmcnt(0). LDS 52 KB -> 3 blocks/CU.
// XCD-chunked remap (2048 = 8*256, bijective): each XCD's L2 sees the whole
// 1 MB wimg + 8 consecutive g-groups' ximg tiles (2 MB) -> L2-hot staging.
// ---------------------------------------------------------------------------
__global__ __launch_bounds__(256, 3) void moe_kernel(
    const bf16* __restrict__ ximg, const bf16* __restrict__ wimg,
    const float* __restrict__ scores_t, float* __restrict__ out)
{
  __shared__ bf16  xl[128 * 64];        // 16384 B
  __shared__ bf16  wl[256 * 64];        // 32768 B  (rows R = e*32 + o)
  __shared__ float sl[NK * 128];        //  4096 B

  int bid = blockIdx.x;
  int lid = ((bid & 7) << 8) | (bid >> 3);   // XCD-chunked, bijective
  int g  = lid >> 5;            // 0..63  (128-token groups)
  int h  = (lid >> 1) & 15;
  int nh = lid & 1;             // col half (32 of the head's 64 out-cols)
  int tid = threadIdx.x, lane = tid & 63, w = tid >> 6;
  int l15 = lane & 15, q = lane >> 4;

  // ---- stage x tile: 4 DMA issues (image layout == LDS layout) ----
  {
    const bf16* xs = ximg + (size_t)(g * 16 + h) * 8192;
#pragma unroll
    for (int it = 0; it < 4; it++)
      GLOAD_LDS16(xs + it * 2048 + tid * 8, xl + it * 2048 + tid * 8);
  }
  // ---- stage W half: 8 DMA issues ----
  {
    const bf16* ws = wimg + (size_t)(h * 2 + nh) * 16384;
#pragma unroll
    for (int it = 0; it < 8; it++)
      GLOAD_LDS16(ws + it * 2048 + tid * 8, wl + it * 2048 + tid * 8);
  }
  // ---- stage scores: 1 DMA issue (sl[k*128+t], offset tid*4 floats) ----
  {
    const float* ss = scores_t + (size_t)(tid >> 5) * BT + g * 128 + (tid & 31) * 4;
    GLOAD_LDS16(ss, sl + tid * 4);
  }
  __syncthreads();

  int mh = w >> 1;              // token half (64 rows)
  int ns = w & 1;               // 16-col slice within the 32-col half

  // ---- B fragments: B[i=ki*32+q*8+j][o=ns*16+l15], all 8 experts ----
  bf16x8 b[NK][2];
#pragma unroll
  for (int e = 0; e < NK; e++) {
    int R = e * 32 + ns * 16 + l15;
#pragma unroll
    for (int ki = 0; ki < 2; ki++) {
      int pc = (ki * 4 + q) ^ (R & 7);
      b[e][ki] = *(const bf16x8*)(wl + R * 64 + pc * 8);
    }
  }

#pragma unroll
  for (int m = 0; m < 4; m++) {
    int tr = mh * 64 + m * 16;                 // token row base in block
    int row = tr + l15;
    int p0 = q ^ (row & 7), p1 = (q + 4) ^ (row & 7);
    bf16x8 a0 = *(const bf16x8*)(xl + row * 64 + p0 * 8);
    bf16x8 a1 = *(const bf16x8*)(xl + row * 64 + p1 * 8);
    floatx4 y = (floatx4){0.f, 0.f, 0.f, 0.f};
#pragma unroll
    for (int e = 0; e < NK; e++) {
      floatx4 s4 = *(const floatx4*)(sl + e * 128 + tr + q * 4);
      floatx4 z = (floatx4){0.f, 0.f, 0.f, 0.f};
      z = __builtin_amdgcn_mfma_f32_16x16x32_bf16(a0, b[e][0], z, 0, 0, 0);
      z = __builtin_amdgcn_mfma_f32_16x16x32_bf16(a1, b[e][1], z, 0, 0, 0);
      y += s4 * z;
    }
    // store: C/D layout col=l15, row=q*4+r
    int orow = g * 128 + tr + q * 4;
    float* op = out + (size_t)orow * (NH * DO) + h * DO + nh * 32 + ns * 16 + l15;
#pragma unroll
    for (int r = 0; r < 4; r++)
      op[(size_t)r * (NH * DO)] = y[r];
  }
}

extern "C" void kernel_launch(void* const* d_in, const int* in_sizes, int n_in,
                              void* d_out, int out_size, void* d_ws, size_t ws_size,
                              hipStream_t stream) {
  const float* x      = (const float*)d_in[0];
  const float* weight = (const float*)d_in[1];
  const float* diag   = (const float*)d_in[2];
  const float* phi    = (const float*)d_in[3];
  float* out = (float*)d_out;

  // workspace: [0,1MiB) wimg | [2MiB) scores_t 256KiB | [4MiB) ximg 16MiB
  bf16*  wimg     = (bf16*)d_ws;
  float* scores_t = (float*)((char*)d_ws + (2u << 20));
  bf16*  ximg     = (bf16*)((char*)d_ws + (4u << 20));

  prep_kernel<<<BT / 4 + NH * NK, 256, 0, stream>>>(x, weight, diag, phi,
                                                    scores_t, wimg, ximg);
  // 64 token-groups x 16 heads x 2 col-halves (XCD-remapped in-kernel)
  moe_kernel<<<64 * NH * 2, 256, 0, stream>>>(ximg, wimg, scores_t, out);
}